// Round 10
// baseline (928.869 us; speedup 1.0000x reference)
//
#include <hip/hip_runtime.h>
#include <math.h>

#define K 128
#define V 50257
#define D 128
#define H 128
#define B 256
#define T 1024
#define NLB 256
#define WPB 197   // 256*197 = 50432 >= V

typedef _Float16 h2 __attribute__((ext_vector_type(2)));
typedef __fp16 fp16x2 __attribute__((ext_vector_type(2)));

__device__ __forceinline__ h2 h2cast(unsigned int u) { return __builtin_bit_cast(h2, u); }
__device__ __forceinline__ unsigned pkdup(float x) {
  fp16x2 v = __builtin_amdgcn_cvt_pkrtz(x, x);
  return __builtin_bit_cast(unsigned, v);
}

// ---- DPP wave reduces (result valid in lane 63) ----
__device__ __forceinline__ float wave_max63(float x) {
  int xi;
#define MSTEP(ctrl, rm, bm)                                                          \
  xi = __builtin_amdgcn_update_dpp(__float_as_int(x), __float_as_int(x), ctrl, rm,   \
                                   bm, false);                                       \
  x = fmaxf(x, __int_as_float(xi));
  MSTEP(0x111, 0xf, 0xf)  // row_shr:1
  MSTEP(0x112, 0xf, 0xf)  // row_shr:2
  MSTEP(0x114, 0xf, 0xe)  // row_shr:4
  MSTEP(0x118, 0xf, 0xc)  // row_shr:8
  MSTEP(0x142, 0xa, 0xf)  // row_bcast:15
  MSTEP(0x143, 0xc, 0xf)  // row_bcast:31
#undef MSTEP
  return x;
}
__device__ __forceinline__ float wave_sum63(float x) {
  int xi;
#define SSTEP(ctrl, rm, bm)                                                          \
  xi = __builtin_amdgcn_update_dpp(0, __float_as_int(x), ctrl, rm, bm, true);        \
  x = x + __int_as_float(xi);
  SSTEP(0x111, 0xf, 0xf)
  SSTEP(0x112, 0xf, 0xf)
  SSTEP(0x114, 0xf, 0xe)
  SSTEP(0x118, 0xf, 0xc)
  SSTEP(0x142, 0xa, 0xf)
  SSTEP(0x143, 0xc, 0xf)
#undef SSTEP
  return x;
}

// scoresT[w][k] = dot(tag[k], word[w]) + bias[w]; thread-per-word, tags in LDS
__global__ void __launch_bounds__(256) k_scores(const float* __restrict__ tag_w,
                                                const float* __restrict__ word_w,
                                                const float* __restrict__ word_b,
                                                float* __restrict__ scoresT) {
  __shared__ __align__(16) float tg[K][D];  // 64 KB
  int tid = threadIdx.x;
#pragma unroll
  for (int q = 0; q < 16; q++) {
    int f4 = q * 256 + tid;
    ((float4*)tg)[f4] = ((const float4*)tag_w)[f4];
  }
  __syncthreads();
  int w = blockIdx.x * 256 + tid;
  if (w >= V) return;
  float wb = word_b[w];
  float4 wreg[32];
#pragma unroll
  for (int c = 0; c < 32; c++) wreg[c] = *(const float4*)(word_w + (size_t)w * D + 4 * c);
  for (int k4 = 0; k4 < 32; k4++) {
    float4 out;
    float* op = (float*)&out;
#pragma unroll
    for (int kk = 0; kk < 4; kk++) {
      int k = k4 * 4 + kk;
      float a0 = 0, a1 = 0, a2 = 0, a3 = 0;
#pragma unroll
      for (int c = 0; c < 32; c++) {
        float4 t4 = *(const float4*)&tg[k][4 * c];
        a0 = fmaf(t4.x, wreg[c].x, a0);
        a1 = fmaf(t4.y, wreg[c].y, a1);
        a2 = fmaf(t4.z, wreg[c].z, a2);
        a3 = fmaf(t4.w, wreg[c].w, a3);
      }
      op[kk] = (a0 + a1) + (a2 + a3) + wb;
    }
    *(float4*)&scoresT[(size_t)w * K + 4 * k4] = out;
  }
}

// per-k online (max,sumexp) over a word slice
__global__ void __launch_bounds__(256) k_collse(const float* __restrict__ scoresT,
                                                float* __restrict__ pmax,
                                                float* __restrict__ psum) {
  int tid = threadIdx.x;
  int blk = blockIdx.x;
  int k = tid & 127, half = tid >> 7;
  int w0 = blk * WPB;
  int wend = min(w0 + WPB, V);
  float m = -1e30f, s = 0.f;
  for (int w = w0 + half; w < wend; w += 2) {
    float v = scoresT[(size_t)w * K + k];
    if (v > m) { s *= __expf(m - v); m = v; }
    s += __expf(v - m);
  }
  pmax[blk * 256 + tid] = m;
  psum[blk * 256 + tid] = s;
}

__global__ void k_lsefin(const float* __restrict__ pmax, const float* __restrict__ psum,
                         float* __restrict__ lse) {
  __shared__ float sm[2][K], ss[2][K];
  int tid = threadIdx.x;
  int k = tid & 127, half = tid >> 7;
  float m = -1e30f, s = 0.f;
  for (int blk = 0; blk < NLB; blk++) {
    float pm = pmax[blk * 256 + half * 128 + k];
    float pv = psum[blk * 256 + half * 128 + k];
    float nm = fmaxf(m, pm);
    s = s * __expf(m - nm) + pv * __expf(pm - nm);
    m = nm;
  }
  sm[half][k] = m;
  ss[half][k] = s;
  __syncthreads();
  if (tid < K) {
    float nm = fmaxf(sm[0][tid], sm[1][tid]);
    float st = ss[0][tid] * __expf(sm[0][tid] - nm) + ss[1][tid] * __expf(sm[1][tid] - nm);
    lse[tid] = nm + __logf(st);
  }
}

// mB[w] = max_k (score[w][k] - lse[k])
__global__ void __launch_bounds__(256) k_rowmax(const float* __restrict__ scoresT,
                                                const float* __restrict__ lse,
                                                float* __restrict__ mB) {
  __shared__ __align__(16) float ls[K];
  int tid = threadIdx.x;
  if (tid < K) ls[tid] = lse[tid];
  __syncthreads();
  int w = blockIdx.x * 256 + tid;
  if (w >= V) return;
  const float* row = scoresT + (size_t)w * K;
  float mx = -1e30f;
#pragma unroll
  for (int c = 0; c < 32; c++) {
    float4 s4 = *(const float4*)&row[4 * c];
    float4 l4 = *(const float4*)&ls[4 * c];
    mx = fmaxf(mx, fmaxf(fmaxf(s4.x - l4.x, s4.y - l4.y), fmaxf(s4.z - l4.z, s4.w - l4.w)));
  }
  mB[w] = mx;
}

// Ahp: pair-column f16 layout: Ahp[cp*256 + 2*i + par] = A[i][2*cp+par]
__global__ void k_transA(const float* __restrict__ trans_w, const float* __restrict__ trans_b,
                         const float* __restrict__ trans_q, _Float16* __restrict__ Ahp) {
  __shared__ __align__(16) float qs[H];
  __shared__ float red[2];
  int i = blockIdx.x;
  int j = threadIdx.x;
  qs[j] = trans_q[j];
  __syncthreads();
  const float* wrow = trans_w + (size_t)(i * K + j) * H;
  float acc = 0.f;
#pragma unroll
  for (int h = 0; h < H; h += 4) {
    float4 w4 = *(const float4*)(wrow + h);
    float4 q4 = *(const float4*)(qs + h);
    acc += w4.x * q4.x + w4.y * q4.y + w4.z * q4.z + w4.w * q4.w;
  }
  float logit = acc + trans_b[i * K + j];
  int wid = j >> 6;
  float m = logit;
  for (int o = 32; o; o >>= 1) m = fmaxf(m, __shfl_xor(m, o, 64));
  if ((j & 63) == 0) red[wid] = m;
  __syncthreads();
  m = fmaxf(red[0], red[1]);
  __syncthreads();
  float e = __expf(logit - m);
  float s = e;
  for (int o = 32; o; o >>= 1) s += __shfl_xor(s, o, 64);
  if ((j & 63) == 0) red[wid] = s;
  __syncthreads();
  s = red[0] + red[1];
  Ahp[(size_t)(j >> 1) * 256 + 2 * i + (j & 1)] = (_Float16)(e / s);
}

__global__ void k_pi(const float* __restrict__ x, float* __restrict__ pi) {
  int j = threadIdx.x;
  __shared__ float red[2];
  float v = x[j];
  int wid = j >> 6;
  float m = v;
  for (int o = 32; o; o >>= 1) m = fmaxf(m, __shfl_xor(m, o, 64));
  if ((j & 63) == 0) red[wid] = m;
  __syncthreads();
  m = fmaxf(red[0], red[1]);
  __syncthreads();
  float e = __expf(v - m);
  float s = e;
  for (int o = 32; o; o >>= 1) s += __shfl_xor(s, o, 64);
  if ((j & 63) == 0) red[wid] = s;
  __syncthreads();
  s = red[0] + red[1];
  pi[j] = e / (red[0] + red[1]);
}

// 1-wave forward recurrence: 2 states/lane, A pair-cols in padded LDS (zero addr VALU),
// p as duplicated-f16 dwords in LDS, phi-static 4x-unrolled prefetch, no barriers.
__global__ void __launch_bounds__(64, 1) k_forward(
    const int* __restrict__ emis, const float* __restrict__ scoresT,
    const float* __restrict__ lse, const float* __restrict__ mB,
    const _Float16* __restrict__ Ahp, const float* __restrict__ pi,
    float* __restrict__ sll) {
  __shared__ __align__(16) _Float16 Alds[64 * 264];  // 33 uint4/col (16B pad) = 33.8 KB
  __shared__ __align__(16) unsigned psD[K];          // dup'd f16 pairs, 512 B
  __shared__ int es[T + 8];
  int b = blockIdx.x;
  int l = threadIdx.x;  // owns states 2l, 2l+1
  for (int i = l; i < T + 8; i += 64) es[i] = emis[b * T + (i < T ? i : T - 1)];
  {
    const uint4* src = (const uint4*)Ahp;
    uint4* dst = (uint4*)Alds;
#pragma unroll
    for (int u = 0; u < 32; ++u) dst[l * 33 + u] = src[l * 32 + u];
  }
  float2 lse2 = *(const float2*)(lse + 2 * l);
  float2 pi2 = *(const float2*)(pi + 2 * l);
  __syncthreads();
  // prologue t=0
  int w0 = es[0];
  float2 sc0 = *(const float2*)(scoresT + (size_t)w0 * K + 2 * l);
  float mb0 = mB[w0];
  float pnx = pi2.x * __expf(sc0.x - lse2.x - mb0);
  float pny = pi2.y * __expf(sc0.y - lse2.y - mb0);
  *(uint2*)&psD[2 * l] = make_uint2(pkdup(pnx), pkdup(pny));
  float Cacc = mb0;
  float zm0 = wave_max63(fmaxf(pnx, pny));
  float z = __int_as_float(__builtin_amdgcn_readlane(__float_as_int(zm0), 63));
  // phi-static score pipeline: s_phi holds word (t) for next t with t&3==phi
  float2 s1 = *(const float2*)(scoresT + (size_t)es[1] * K + 2 * l);
  float m1 = mB[es[1]];
  float2 s2 = *(const float2*)(scoresT + (size_t)es[2] * K + 2 * l);
  float m2 = mB[es[2]];
  float2 s3 = *(const float2*)(scoresT + (size_t)es[3] * K + 2 * l);
  float m3 = mB[es[3]];
  float2 s0 = *(const float2*)(scoresT + (size_t)es[4] * K + 2 * l);
  float m0 = mB[es[4]];
  asm volatile("s_waitcnt lgkmcnt(0)" ::: "memory");
  const uint4* AV = (const uint4*)Alds;
  int abase = l * 33;
  int esidx = 5;

#define STEP(PH)                                                                     \
  {                                                                                  \
    float zz = fmaxf(z, 1e-30f);                                                     \
    float rr = __builtin_amdgcn_rcpf(zz);                                            \
    float lzp = __logf(zz);                                                          \
    float lmb = m##PH;                                                               \
    float ebx = __expf(s##PH.x - lse2.x - lmb) * rr;                                 \
    float eby = __expf(s##PH.y - lse2.y - lmb) * rr;                                 \
    int wnew = es[esidx];                                                            \
    esidx++;                                                                         \
    s##PH = *(const float2*)(scoresT + (size_t)wnew * K + 2 * l);                    \
    m##PH = mB[wnew];                                                                \
    h2 qa = (h2)0, qb = (h2)0, qc = (h2)0, qd = (h2)0;                               \
    _Pragma("unroll") for (int u = 0; u < 32; ++u) {                                 \
      uint4 Au = AV[abase + u];                                                      \
      uint4 Pd = *(const uint4*)&psD[4 * u];                                         \
      qa = __builtin_elementwise_fma(h2cast(Pd.x), h2cast(Au.x), qa);                \
      qb = __builtin_elementwise_fma(h2cast(Pd.y), h2cast(Au.y), qb);                \
      qc = __builtin_elementwise_fma(h2cast(Pd.z), h2cast(Au.z), qc);                \
      qd = __builtin_elementwise_fma(h2cast(Pd.w), h2cast(Au.w), qd);                \
    }                                                                                \
    h2 qs = (qa + qb) + (qc + qd);                                                   \
    pnx = (float)qs.x * ebx;                                                         \
    pny = (float)qs.y * eby;                                                         \
    Cacc += lzp + lmb;                                                               \
    *(uint2*)&psD[2 * l] = make_uint2(pkdup(pnx), pkdup(pny));                       \
    asm volatile("s_waitcnt lgkmcnt(0)" ::: "memory");                               \
    float zm = wave_max63(fmaxf(pnx, pny));                                          \
    z = __int_as_float(__builtin_amdgcn_readlane(__float_as_int(zm), 63));           \
  }

  for (int g = 0; g < 255; ++g) {
    STEP(1) STEP(2) STEP(3) STEP(0)
  }
  STEP(1) STEP(2) STEP(3)   // t = 1021, 1022, 1023
#undef STEP

  float ssum = wave_sum63(pnx + pny);
  if (l == 63) sll[b] = Cacc + __logf(ssum);
}

__global__ void k_loss(const float* __restrict__ sll, float* __restrict__ out) {
  int tid = threadIdx.x;
  __shared__ float red[4];
  float v = sll[tid];
#pragma unroll
  for (int o = 32; o; o >>= 1) v += __shfl_xor(v, o, 64);
  if ((tid & 63) == 0) red[tid >> 6] = v;
  __syncthreads();
  if (tid == 0) out[0] = -(red[0] + red[1] + red[2] + red[3]) / (float)B;
}

extern "C" void kernel_launch(void* const* d_in, const int* in_sizes, int n_in,
                              void* d_out, int out_size, void* d_ws, size_t ws_size,
                              hipStream_t stream) {
  const int*   emis   = (const int*)d_in[0];
  const float* initl  = (const float*)d_in[1];
  const float* tagw   = (const float*)d_in[2];
  const float* wordw  = (const float*)d_in[3];
  const float* wordb  = (const float*)d_in[4];
  const float* transw = (const float*)d_in[5];
  const float* transb = (const float*)d_in[6];
  const float* transq = (const float*)d_in[7];
  float* ws = (float*)d_ws;
  size_t off = 0;
  float* scoresT = ws + off; off += (size_t)V * K;
  _Float16* Ahp  = (_Float16*)(ws + off); off += (size_t)K * K / 2;
  float* pivec   = ws + off; off += K;
  float* lse     = ws + off; off += K;
  float* pmax    = ws + off; off += (size_t)NLB * 256;
  float* psum    = ws + off; off += (size_t)NLB * 256;
  float* mB      = ws + off; off += (size_t)V + 64;
  float* sll     = ws + off; off += B;
  float* out = (float*)d_out;

  hipLaunchKernelGGL(k_transA, dim3(K), dim3(K), 0, stream, transw, transb, transq, Ahp);
  hipLaunchKernelGGL(k_pi, dim3(1), dim3(K), 0, stream, initl, pivec);
  hipLaunchKernelGGL(k_scores, dim3((V + 255) / 256), dim3(256), 0, stream, tagw, wordw, wordb, scoresT);
  hipLaunchKernelGGL(k_collse, dim3(NLB), dim3(256), 0, stream, scoresT, pmax, psum);
  hipLaunchKernelGGL(k_lsefin, dim3(1), dim3(256), 0, stream, pmax, psum, lse);
  hipLaunchKernelGGL(k_rowmax, dim3((V + 255) / 256), dim3(256), 0, stream, scoresT, lse, mB);
  hipLaunchKernelGGL(k_forward, dim3(B), dim3(64), 0, stream, emis, scoresT, lse, mB, Ahp, pivec, sll);
  hipLaunchKernelGGL(k_loss, dim3(1), dim3(256), 0, stream, sll, out);
}

// Round 12
// 378.025 us; speedup vs baseline: 2.4572x; 2.4572x over previous
//
#include <hip/hip_runtime.h>
#include <math.h>

#define K 128
#define V 50257
#define H 128
#define B 256
#define T 1024
#define NLB 256
#define WPB 197   // 256*197 >= V

typedef _Float16 half8 __attribute__((ext_vector_type(8)));
typedef float f32x4 __attribute__((ext_vector_type(4)));
typedef __fp16 fp16x2 __attribute__((ext_vector_type(2)));

__device__ __forceinline__ unsigned pkh2(float x, float y) {
  fp16x2 v = __builtin_amdgcn_cvt_pkrtz(x, y);
  return __builtin_bit_cast(unsigned, v);
}
__device__ __forceinline__ unsigned short f16b(float x) {
  fp16x2 v = __builtin_amdgcn_cvt_pkrtz(x, x);
  return (unsigned short)(__builtin_bit_cast(unsigned, v) & 0xFFFFu);
}

// DPP wave max (result valid in lane 63)
__device__ __forceinline__ float wave_max63(float x) {
  int xi;
#define MSTEP(ctrl, rm, bm)                                                          \
  xi = __builtin_amdgcn_update_dpp(__float_as_int(x), __float_as_int(x), ctrl, rm,   \
                                   bm, false);                                       \
  x = fmaxf(x, __int_as_float(xi));
  MSTEP(0x111, 0xf, 0xf)
  MSTEP(0x112, 0xf, 0xf)
  MSTEP(0x114, 0xf, 0xe)
  MSTEP(0x118, 0xf, 0xc)
  MSTEP(0x142, 0xa, 0xf)
  MSTEP(0x143, 0xc, 0xf)
#undef MSTEP
  return x;
}

// scoresH[w][k] (f16) = dot(tag[k], word[w]) + bias[w]
__global__ void __launch_bounds__(256) k_scores(const float* __restrict__ tag_w,
                                                const float* __restrict__ word_w,
                                                const float* __restrict__ word_b,
                                                _Float16* __restrict__ scoresH) {
  __shared__ __align__(16) float tg[K][K];  // 64 KB
  int tid = threadIdx.x;
#pragma unroll
  for (int q = 0; q < 16; q++) {
    int f4 = q * 256 + tid;
    ((float4*)tg)[f4] = ((const float4*)tag_w)[f4];
  }
  __syncthreads();
  int w = blockIdx.x * 256 + tid;
  if (w >= V) return;
  float wb = word_b[w];
  float4 wreg[32];
#pragma unroll
  for (int c = 0; c < 32; c++) wreg[c] = *(const float4*)(word_w + (size_t)w * K + 4 * c);
  for (int k4 = 0; k4 < 32; k4++) {
    float op[4];
#pragma unroll
    for (int kk = 0; kk < 4; kk++) {
      int k = k4 * 4 + kk;
      float a0 = 0, a1 = 0, a2 = 0, a3 = 0;
#pragma unroll
      for (int c = 0; c < 32; c++) {
        float4 t4 = *(const float4*)&tg[k][4 * c];
        a0 = fmaf(t4.x, wreg[c].x, a0);
        a1 = fmaf(t4.y, wreg[c].y, a1);
        a2 = fmaf(t4.z, wreg[c].z, a2);
        a3 = fmaf(t4.w, wreg[c].w, a3);
      }
      op[kk] = (a0 + a1) + (a2 + a3) + wb;
    }
    uint2 pk = make_uint2(pkh2(op[0], op[1]), pkh2(op[2], op[3]));
    *(uint2*)&scoresH[(size_t)w * K + 4 * k4] = pk;
  }
}

// per-k online (max,sumexp) over a word slice (f16 scores in)
__global__ void __launch_bounds__(256) k_collse(const _Float16* __restrict__ scoresH,
                                                float* __restrict__ pmax,
                                                float* __restrict__ psum) {
  int tid = threadIdx.x;
  int blk = blockIdx.x;
  int k = tid & 127, half = tid >> 7;
  int w0 = blk * WPB;
  int wend = min(w0 + WPB, V);
  float m = -1e30f, s = 0.f;
  for (int w = w0 + half; w < wend; w += 2) {
    float v = (float)scoresH[(size_t)w * K + k];
    if (v > m) { s *= __expf(m - v); m = v; }
    s += __expf(v - m);
  }
  pmax[blk * 256 + tid] = m;
  psum[blk * 256 + tid] = s;
}

__global__ void k_lsefin(const float* __restrict__ pmax, const float* __restrict__ psum,
                         float* __restrict__ lse) {
  __shared__ float sm[2][K], ss[2][K];
  int tid = threadIdx.x;
  int k = tid & 127, half = tid >> 7;
  float m = -1e30f, s = 0.f;
  for (int blk = 0; blk < NLB; blk++) {
    float pm = pmax[blk * 256 + half * 128 + k];
    float pv = psum[blk * 256 + half * 128 + k];
    float nm = fmaxf(m, pm);
    s = s * __expf(m - nm) + pv * __expf(pm - nm);
    m = nm;
  }
  sm[half][k] = m;
  ss[half][k] = s;
  __syncthreads();
  if (tid < K) {
    float nm = fmaxf(sm[0][tid], sm[1][tid]);
    float st = ss[0][tid] * __expf(sm[0][tid] - nm) + ss[1][tid] * __expf(sm[1][tid] - nm);
    lse[tid] = nm + __logf(st);
  }
}

// mB[w] = max_k (score[w][k] - lse[k])
__global__ void __launch_bounds__(256) k_rowmax(const _Float16* __restrict__ scoresH,
                                                const float* __restrict__ lse,
                                                float* __restrict__ mB) {
  __shared__ __align__(16) float ls[K];
  int tid = threadIdx.x;
  if (tid < K) ls[tid] = lse[tid];
  __syncthreads();
  int w = blockIdx.x * 256 + tid;
  if (w >= V) return;
  const uint4* rowv = (const uint4*)(scoresH + (size_t)w * K);
  float mx = -1e30f;
#pragma unroll
  for (int c = 0; c < 16; c++) {
    uint4 u = rowv[c];
    const _Float16* hp = (const _Float16*)&u;
#pragma unroll
    for (int d = 0; d < 8; d++) mx = fmaxf(mx, (float)hp[d] - ls[8 * c + d]);
  }
  mB[w] = mx;
}

// in place: scoresH[w][k] -> exp(score - lse[k] - mB[w])   (f16, values in (0,1])
__global__ void __launch_bounds__(256) k_expb(_Float16* __restrict__ scoresH,
                                              const float* __restrict__ lse,
                                              const float* __restrict__ mB) {
  __shared__ __align__(16) float ls[K];
  int tid = threadIdx.x;
  if (tid < K) ls[tid] = lse[tid];
  __syncthreads();
  int w = blockIdx.x * 256 + tid;
  if (w >= V) return;
  float mbw = mB[w];
  uint4* rowv = (uint4*)(scoresH + (size_t)w * K);
#pragma unroll
  for (int c = 0; c < 16; c++) {
    uint4 u = rowv[c];
    const _Float16* hp = (const _Float16*)&u;
    float e[8];
#pragma unroll
    for (int d = 0; d < 8; d++) e[d] = __expf((float)hp[d] - ls[8 * c + d] - mbw);
    uint4 o;
    o.x = pkh2(e[0], e[1]); o.y = pkh2(e[2], e[3]);
    o.z = pkh2(e[4], e[5]); o.w = pkh2(e[6], e[7]);
    rowv[c] = o;
  }
}

// Ahat (row-softmax of trans logits) written as f16 B-fragments for mfma 16x16x32:
// state i -> kt=(i>>5), g=((i&31)>>3), e=i&7 ; lane=16*g+(j&15), n=j>>4
__global__ void k_transA(const float* __restrict__ trans_w, const float* __restrict__ trans_b,
                         const float* __restrict__ trans_q, unsigned short* __restrict__ AbfH) {
  __shared__ __align__(16) float qs[H];
  __shared__ float red[2];
  int i = blockIdx.x;
  int j = threadIdx.x;
  qs[j] = trans_q[j];
  __syncthreads();
  const float* wrow = trans_w + (size_t)(i * K + j) * H;
  float acc = 0.f;
#pragma unroll
  for (int h = 0; h < H; h += 4) {
    float4 w4 = *(const float4*)(wrow + h);
    float4 q4 = *(const float4*)(qs + h);
    acc += w4.x * q4.x + w4.y * q4.y + w4.z * q4.z + w4.w * q4.w;
  }
  float logit = acc + trans_b[i * K + j];
  int wid = j >> 6;
  float m = logit;
  for (int o = 32; o; o >>= 1) m = fmaxf(m, __shfl_xor(m, o, 64));
  if ((j & 63) == 0) red[wid] = m;
  __syncthreads();
  m = fmaxf(red[0], red[1]);
  __syncthreads();
  float e = __expf(logit - m);
  float s = e;
  for (int o = 32; o; o >>= 1) s += __shfl_xor(s, o, 64);
  if ((j & 63) == 0) red[wid] = s;
  __syncthreads();
  s = red[0] + red[1];
  float a = e / s;
  int kt = i >> 5;
  int g = (i & 31) >> 3;
  int lane = 16 * g + (j & 15);
  int n = j >> 4;
  int ee = i & 7;
  AbfH[(size_t)(((kt * 8 + n) * 64 + lane) * 8 + ee)] = f16b(a);
}

__global__ void k_pi(const float* __restrict__ x, float* __restrict__ pi) {
  int j = threadIdx.x;
  __shared__ float red[2];
  float v = x[j];
  int wid = j >> 6;
  float m = v;
  for (int o = 32; o; o >>= 1) m = fmaxf(m, __shfl_xor(m, o, 64));
  if ((j & 63) == 0) red[wid] = m;
  __syncthreads();
  m = fmaxf(red[0], red[1]);
  __syncthreads();
  float e = __expf(v - m);
  float s = e;
  for (int o = 32; o; o >>= 1) s += __shfl_xor(s, o, 64);
  if ((j & 63) == 0) red[wid] = s;
  __syncthreads();
  s = red[0] + red[1];
  pi[j] = e / s;
}

// chunk-parallel forward: 1 wave = 16 chunks of one chain; 80 steps (16 warmup + 64 counted).
// Per step: Q[16x128] = P f16 . Ahat f16 via 32 mfma; eb+rescale; repack through LDS.
__global__ void __launch_bounds__(64, 1) k_forward(
    const int* __restrict__ emis, const _Float16* __restrict__ expbH,
    const float* __restrict__ mB, const uint4* __restrict__ Abf_g,
    const float* __restrict__ pivec, float* __restrict__ Rbuf) {
  __shared__ __align__(16) uint4 AbfL[4 * 8 * 64];  // 32 KB = 2048 uint4
  __shared__ float Qx[128 * 17];                    // 8.7 KB, [j][m] stride 17
  __shared__ int es[T];
  int b = blockIdx.x;
  int l = threadIdx.x;
  int c = l & 15;   // this lane's chunk
  int g = l >> 4;
  for (int i = l; i < T; i += 64) es[i] = emis[b * T + i];
#pragma unroll
  for (int p = 0; p < 32; p++) AbfL[p * 64 + l] = Abf_g[p * 64 + l];  // FIX: all 2048 uint4
  int Jb[4];
#pragma unroll
  for (int kt = 0; kt < 4; kt++) Jb[kt] = 32 * kt + 8 * g;
  __syncthreads();
  // ---- prologue: exact chunk-0 start ----
  int w0 = es[0];
  float mb0 = mB[w0];
  float a0v = pivec[2 * l] * (float)expbH[(size_t)w0 * K + 2 * l];
  float a1v = pivec[2 * l + 1] * (float)expbH[(size_t)w0 * K + 2 * l + 1];
  float am = wave_max63(fmaxf(a0v, a1v));
  float mu1 = __int_as_float(__builtin_amdgcn_readlane(__float_as_int(am), 63));
  mu1 = fmaxf(mu1, 1e-30f);
  float lmu1 = __logf(mu1);
  uint4 P0[4];
  {
    float inv = 1.0f / mu1;
#pragma unroll
    for (int kt = 0; kt < 4; kt++) {
      float v[8];
#pragma unroll
      for (int i = 0; i < 8; i++) {
        int j = Jb[kt] + i;
        v[i] = pivec[j] * (float)expbH[(size_t)w0 * K + j] * inv;
      }
      P0[kt] = make_uint4(pkh2(v[0], v[1]), pkh2(v[2], v[3]), pkh2(v[4], v[5]), pkh2(v[6], v[7]));
    }
  }
  // ---- init: uniform ones ----
  uint4 Pk[4];
  unsigned one2 = 0x3C003C00u;  // f16 1.0 pair
  Pk[0] = Pk[1] = Pk[2] = Pk[3] = make_uint4(one2, one2, one2, one2);
  float zprev = 1.0f, lzS = 0.f, lzE = 0.f, logS = 0.f, Cacc = 0.f;
  int cend = (c == 15) ? 78 : 79;
  for (int s = 0; s < 80; s++) {
    // token + emission prefetch for this step
    int t = 64 * c + s - 15;
    t = max(t, 0); t = min(t, T - 1);
    int tok = es[t];
    float mb = mB[tok];
    const uint4* ebp = (const uint4*)(expbH + (size_t)tok * K);
    uint4 eb[4];
#pragma unroll
    for (int kt = 0; kt < 4; kt++) eb[kt] = ebp[Jb[kt] >> 3];
    // ---- 32 mfma: acc[n] = sum_kt P[kt] * Abf[kt][n] ----
    f32x4 acc[8];
#pragma unroll
    for (int n = 0; n < 8; n++) acc[n] = (f32x4){0.f, 0.f, 0.f, 0.f};
#pragma unroll
    for (int kt = 0; kt < 4; kt++) {
      half8 ao = __builtin_bit_cast(half8, Pk[kt]);
#pragma unroll
      for (int n = 0; n < 8; n++) {
        half8 bo = __builtin_bit_cast(half8, AbfL[(kt * 8 + n) * 64 + l]);
        acc[n] = __builtin_amdgcn_mfma_f32_16x16x32_f16(ao, bo, acc[n], 0, 0, 0);
      }
    }
    // ---- scatter D to Qx[j][m]: j=16n+(l&15), m=4g+r ----
#pragma unroll
    for (int n = 0; n < 8; n++) {
#pragma unroll
      for (int r = 0; r < 4; r++) Qx[17 * (16 * n + c) + 4 * g + r] = acc[n][r];
    }
    asm volatile("s_waitcnt lgkmcnt(0)" ::: "memory");
    __builtin_amdgcn_sched_barrier(0);
    // ---- gather own chunk, apply eb * (1/zprev), pack f16, track max/sum ----
    float rr = __builtin_amdgcn_rcpf(fmaxf(zprev, 1e-30f));
    float lzp = __logf(fmaxf(zprev, 1e-30f));
    float pmax = 0.f, lsum = 0.f;
    uint4 newP[4];
#pragma unroll
    for (int kt = 0; kt < 4; kt++) {
      const _Float16* ebh = (const _Float16*)&eb[kt];
      float pv[8];
#pragma unroll
      for (int i = 0; i < 8; i++) {
        float q = Qx[17 * (Jb[kt] + i) + c];
        float p = q * (float)ebh[i] * rr;
        pv[i] = p;
        pmax = fmaxf(pmax, p);
        lsum += p;
      }
      newP[kt] = make_uint4(pkh2(pv[0], pv[1]), pkh2(pv[2], pv[3]),
                            pkh2(pv[4], pv[5]), pkh2(pv[6], pv[7]));
    }
    // cross-lane (lanes c, c+16, c+32, c+48) max
    pmax = fmaxf(pmax, __shfl_xor(pmax, 16, 64));
    pmax = fmaxf(pmax, __shfl_xor(pmax, 32, 64));
    float znew = pmax;
    if (s == 15) {
      if (c == 0) {
#pragma unroll
        for (int kt = 0; kt < 4; kt++) newP[kt] = P0[kt];
        znew = 1.0f;
      }
      lzS = __logf(fmaxf(znew, 1e-30f));
    }
    bool counted = (s >= 16) && (s <= cend);
    if (counted) Cacc += lzp + mb;
    if (s == 78) {
      float ssum = lsum + __shfl_xor(lsum, 16, 64);
      ssum += __shfl_xor(ssum, 32, 64);
      logS = __logf(fmaxf(ssum, 1e-30f));
    }
    if (s == 79) lzE = __logf(fmaxf(znew, 1e-30f));
#pragma unroll
    for (int kt = 0; kt < 4; kt++) Pk[kt] = newP[kt];
    zprev = znew;
  }
  if (l < 16) {
    float Rv = Cacc - lzS;
    Rv += (c == 15) ? logS : lzE;
    if (c == 0) Rv += mb0 + lmu1;
    Rbuf[b * 16 + c] = Rv;
  }
}

// sll per chain = sum of 16 chunk R's; loss = -mean
__global__ void k_sll(const float* __restrict__ Rbuf, float* __restrict__ out) {
  int tid = threadIdx.x;  // 256 = chains
  __shared__ float red[4];
  float s = 0.f;
  const float* r = Rbuf + tid * 16;
#pragma unroll
  for (int q = 0; q < 16; q++) s += r[q];
#pragma unroll
  for (int o = 32; o; o >>= 1) s += __shfl_xor(s, o, 64);
  if ((tid & 63) == 0) red[tid >> 6] = s;
  __syncthreads();
  if (tid == 0) out[0] = -(red[0] + red[1] + red[2] + red[3]) / (float)B;
}

extern "C" void kernel_launch(void* const* d_in, const int* in_sizes, int n_in,
                              void* d_out, int out_size, void* d_ws, size_t ws_size,
                              hipStream_t stream) {
  const int*   emis   = (const int*)d_in[0];
  const float* initl  = (const float*)d_in[1];
  const float* tagw   = (const float*)d_in[2];
  const float* wordw  = (const float*)d_in[3];
  const float* wordb  = (const float*)d_in[4];
  const float* transw = (const float*)d_in[5];
  const float* transb = (const float*)d_in[6];
  const float* transq = (const float*)d_in[7];
  float* ws = (float*)d_ws;
  size_t off = 0;
  _Float16* scoresH = (_Float16*)(ws + off); off += (size_t)V * K / 2;  // f16 scores -> expb in place
  uint4* Abf_g      = (uint4*)(ws + off);    off += 8192;                // 32 KB B-fragments
  float* pivec      = ws + off; off += K;
  float* lse        = ws + off; off += K;
  float* pmax       = ws + off; off += (size_t)NLB * 256;
  float* psum       = ws + off; off += (size_t)NLB * 256;
  float* mB         = ws + off; off += (size_t)V + 64;
  float* Rbuf       = ws + off; off += (size_t)B * 16;
  float* out = (float*)d_out;

  hipLaunchKernelGGL(k_scores, dim3((V + 255) / 256), dim3(256), 0, stream, tagw, wordw, wordb, scoresH);
  hipLaunchKernelGGL(k_collse, dim3(NLB), dim3(256), 0, stream, scoresH, pmax, psum);
  hipLaunchKernelGGL(k_lsefin, dim3(1), dim3(256), 0, stream, pmax, psum, lse);
  hipLaunchKernelGGL(k_rowmax, dim3((V + 255) / 256), dim3(256), 0, stream, scoresH, lse, mB);
  hipLaunchKernelGGL(k_expb, dim3((V + 255) / 256), dim3(256), 0, stream, scoresH, lse, mB);
  hipLaunchKernelGGL(k_transA, dim3(K), dim3(K), 0, stream, transw, transb, transq, (unsigned short*)Abf_g);
  hipLaunchKernelGGL(k_pi, dim3(1), dim3(K), 0, stream, initl, pivec);
  hipLaunchKernelGGL(k_forward, dim3(B), dim3(64), 0, stream, emis, scoresH, mB, Abf_g, pivec, Rbuf);
  hipLaunchKernelGGL(k_sll, dim3(1), dim3(256), 0, stream, Rbuf, out);
}

// Round 14
// 208.580 us; speedup vs baseline: 4.4533x; 1.8124x over previous
//
#include <hip/hip_runtime.h>
#include <math.h>

#define K 128
#define V 50257
#define H 128
#define B 256
#define T 1024
#define NLB 256
#define WPB 197   // 256*197 >= V

typedef _Float16 half8 __attribute__((ext_vector_type(8)));
typedef float f32x4 __attribute__((ext_vector_type(4)));
typedef __fp16 fp16x2 __attribute__((ext_vector_type(2)));

__device__ __forceinline__ unsigned pkh2(float x, float y) {
  fp16x2 v = __builtin_amdgcn_cvt_pkrtz(x, y);
  return __builtin_bit_cast(unsigned, v);
}
__device__ __forceinline__ unsigned short f16b(float x) {
  fp16x2 v = __builtin_amdgcn_cvt_pkrtz(x, x);
  return (unsigned short)(__builtin_bit_cast(unsigned, v) & 0xFFFFu);
}

// DPP wave max (result valid in lane 63)
__device__ __forceinline__ float wave_max63(float x) {
  int xi;
#define MSTEP(ctrl, rm, bm)                                                          \
  xi = __builtin_amdgcn_update_dpp(__float_as_int(x), __float_as_int(x), ctrl, rm,   \
                                   bm, false);                                       \
  x = fmaxf(x, __int_as_float(xi));
  MSTEP(0x111, 0xf, 0xf)
  MSTEP(0x112, 0xf, 0xf)
  MSTEP(0x114, 0xf, 0xe)
  MSTEP(0x118, 0xf, 0xc)
  MSTEP(0x142, 0xa, 0xf)
  MSTEP(0x143, 0xc, 0xf)
#undef MSTEP
  return x;
}

// tag B-fragments (f16) for mfma_f32_16x16x32_f16, layout verified in R12:
// Tbf[((kt*8+n)*64 + lane)] holds 8 f16: tag[k=16n+(lane&15)][d=32kt+8*(lane>>4)+e]
__global__ void __launch_bounds__(256) k_tagh(const float* __restrict__ tag_w,
                                              uint4* __restrict__ Tbf) {
  int f = blockIdx.x * 256 + threadIdx.x;
  if (f >= 2048) return;
  int lane = f & 63;
  int rest = f >> 6;
  int n = rest & 7, kt = rest >> 3;
  int k = 16 * n + (lane & 15);
  int d0 = 32 * kt + 8 * (lane >> 4);
  const float* src = tag_w + (size_t)k * K + d0;
  float4 a = *(const float4*)src;
  float4 c = *(const float4*)(src + 4);
  Tbf[f] = make_uint4(pkh2(a.x, a.y), pkh2(a.z, a.w), pkh2(c.x, c.y), pkh2(c.z, c.w));
}

// scoresH[w][k] = dot(tag[k], word[w]) + bias[w]  -- MFMA, 64 words/block
__global__ void __launch_bounds__(256) k_scores(const float* __restrict__ word_w,
                                                const float* __restrict__ word_b,
                                                const uint4* __restrict__ Tbf,
                                                _Float16* __restrict__ scoresH) {
  __shared__ __align__(16) uint4 TbfL[2048];        // 32 KB
  __shared__ __align__(16) _Float16 outT[64][136];  // 17.4 KB, padded rows (272 B)
  int tid = threadIdx.x;
  int wv = tid >> 6, l = tid & 63;
  int c = l & 15, g = l >> 4;
  int wbase = blockIdx.x * 64;
#pragma unroll
  for (int q = 0; q < 8; q++) TbfL[q * 256 + tid] = Tbf[q * 256 + tid];
  // A-fragments: lane supplies word row (l&15), dims 32kt+8g..+7
  int wa = min(wbase + wv * 16 + c, V - 1);
  const float* wrow = word_w + (size_t)wa * K + 8 * g;
  uint4 A0, A1, A2, A3;
#define LDA(kt, dst)                                                        \
  {                                                                         \
    float4 x = *(const float4*)(wrow + 32 * kt);                            \
    float4 y = *(const float4*)(wrow + 32 * kt + 4);                        \
    dst = make_uint4(pkh2(x.x, x.y), pkh2(x.z, x.w), pkh2(y.x, y.y), pkh2(y.z, y.w)); \
  }
  LDA(0, A0) LDA(1, A1) LDA(2, A2) LDA(3, A3)
#undef LDA
  float wb[4];
#pragma unroll
  for (int r = 0; r < 4; r++) wb[r] = word_b[min(wbase + wv * 16 + 4 * g + r, V - 1)];
  __syncthreads();
  f32x4 acc[8];
#pragma unroll
  for (int n = 0; n < 8; n++) acc[n] = (f32x4){0.f, 0.f, 0.f, 0.f};
#define MK(kt, AV)                                                          \
  {                                                                         \
    half8 ao = __builtin_bit_cast(half8, AV);                               \
    _Pragma("unroll") for (int n = 0; n < 8; n++) {                         \
      half8 bo = __builtin_bit_cast(half8, TbfL[(kt * 8 + n) * 64 + l]);    \
      acc[n] = __builtin_amdgcn_mfma_f32_16x16x32_f16(ao, bo, acc[n], 0, 0, 0); \
    }                                                                       \
  }
  MK(0, A0) MK(1, A1) MK(2, A2) MK(3, A3)
#undef MK
  // scatter D + bias: D row = 4g+r (word), col = 16n+c (tag)
#pragma unroll
  for (int n = 0; n < 8; n++) {
#pragma unroll
    for (int r = 0; r < 4; r++)
      outT[wv * 16 + 4 * g + r][16 * n + c] = (_Float16)(acc[n][r] + wb[r]);
  }
  __syncthreads();
  // coalesced f16 stores: 1024 uint4 per block (16 per word row)
#pragma unroll
  for (int q = 0; q < 4; q++) {
    int idx = q * 256 + tid;
    int wl = idx >> 4, part = idx & 15;
    int w = wbase + wl;
    if (w < V) {
      uint4 v = *(const uint4*)&outT[wl][part * 8];
      *(uint4*)&scoresH[(size_t)w * K + part * 8] = v;
    }
  }
}

// per-k online (max,sumexp) over a word slice (f16 scores in)
__global__ void __launch_bounds__(256) k_collse(const _Float16* __restrict__ scoresH,
                                                float* __restrict__ pmax,
                                                float* __restrict__ psum) {
  int tid = threadIdx.x;
  int blk = blockIdx.x;
  int k = tid & 127, half = tid >> 7;
  int w0 = blk * WPB;
  int wend = min(w0 + WPB, V);
  float m = -1e30f, s = 0.f;
  for (int w = w0 + half; w < wend; w += 2) {
    float v = (float)scoresH[(size_t)w * K + k];
    if (v > m) { s *= __expf(m - v); m = v; }
    s += __expf(v - m);
  }
  pmax[blk * 256 + tid] = m;
  psum[blk * 256 + tid] = s;
}

__global__ void k_lsefin(const float* __restrict__ pmax, const float* __restrict__ psum,
                         float* __restrict__ lse) {
  __shared__ float sm[2][K], ss[2][K];
  int tid = threadIdx.x;
  int k = tid & 127, half = tid >> 7;
  float m = -1e30f, s = 0.f;
  for (int blk = 0; blk < NLB; blk++) {
    float pm = pmax[blk * 256 + half * 128 + k];
    float pv = psum[blk * 256 + half * 128 + k];
    float nm = fmaxf(m, pm);
    s = s * __expf(m - nm) + pv * __expf(pm - nm);
    m = nm;
  }
  sm[half][k] = m;
  ss[half][k] = s;
  __syncthreads();
  if (tid < K) {
    float nm = fmaxf(sm[0][tid], sm[1][tid]);
    float st = ss[0][tid] * __expf(sm[0][tid] - nm) + ss[1][tid] * __expf(sm[1][tid] - nm);
    lse[tid] = nm + __logf(st);
  }
}

// fused: mB[w] = max_k(score-lse), then in-place scoresH -> exp(score-lse-mB)
__global__ void __launch_bounds__(256) k_expbm(_Float16* __restrict__ scoresH,
                                               const float* __restrict__ lse,
                                               float* __restrict__ mB) {
  __shared__ __align__(16) float ls[K];
  int tid = threadIdx.x;
  if (tid < K) ls[tid] = lse[tid];
  __syncthreads();
  int w = blockIdx.x * 256 + tid;
  if (w >= V) return;
  uint4* rowv = (uint4*)(scoresH + (size_t)w * K);
  float mx = -1e30f;
#pragma unroll
  for (int c = 0; c < 16; c++) {
    uint4 u = rowv[c];
    const _Float16* hp = (const _Float16*)&u;
#pragma unroll
    for (int d = 0; d < 8; d++) mx = fmaxf(mx, (float)hp[d] - ls[8 * c + d]);
  }
  mB[w] = mx;
#pragma unroll
  for (int c = 0; c < 16; c++) {
    uint4 u = rowv[c];
    const _Float16* hp = (const _Float16*)&u;
    float e[8];
#pragma unroll
    for (int d = 0; d < 8; d++) e[d] = __expf((float)hp[d] - ls[8 * c + d] - mx);
    uint4 o;
    o.x = pkh2(e[0], e[1]); o.y = pkh2(e[2], e[3]);
    o.z = pkh2(e[4], e[5]); o.w = pkh2(e[6], e[7]);
    rowv[c] = o;
  }
}

// Ahat (row-softmax of trans logits) as f16 B-fragments (R12-verified layout)
__global__ void k_transA(const float* __restrict__ trans_w, const float* __restrict__ trans_b,
                         const float* __restrict__ trans_q, unsigned short* __restrict__ AbfH) {
  __shared__ __align__(16) float qs[H];
  __shared__ float red[2];
  int i = blockIdx.x;
  int j = threadIdx.x;
  qs[j] = trans_q[j];
  __syncthreads();
  const float* wrow = trans_w + (size_t)(i * K + j) * H;
  float acc = 0.f;
#pragma unroll
  for (int h = 0; h < H; h += 4) {
    float4 w4 = *(const float4*)(wrow + h);
    float4 q4 = *(const float4*)(qs + h);
    acc += w4.x * q4.x + w4.y * q4.y + w4.z * q4.z + w4.w * q4.w;
  }
  float logit = acc + trans_b[i * K + j];
  int wid = j >> 6;
  float m = logit;
  for (int o = 32; o; o >>= 1) m = fmaxf(m, __shfl_xor(m, o, 64));
  if ((j & 63) == 0) red[wid] = m;
  __syncthreads();
  m = fmaxf(red[0], red[1]);
  __syncthreads();
  float e = __expf(logit - m);
  float s = e;
  for (int o = 32; o; o >>= 1) s += __shfl_xor(s, o, 64);
  if ((j & 63) == 0) red[wid] = s;
  __syncthreads();
  s = red[0] + red[1];
  float a = e / s;
  int kt = i >> 5;
  int g = (i & 31) >> 3;
  int lane = 16 * g + (j & 15);
  int n = j >> 4;
  int ee = i & 7;
  AbfH[(size_t)(((kt * 8 + n) * 64 + lane) * 8 + ee)] = f16b(a);
}

__global__ void k_pi(const float* __restrict__ x, float* __restrict__ pi) {
  int j = threadIdx.x;
  __shared__ float red[2];
  float v = x[j];
  int wid = j >> 6;
  float m = v;
  for (int o = 32; o; o >>= 1) m = fmaxf(m, __shfl_xor(m, o, 64));
  if ((j & 63) == 0) red[wid] = m;
  __syncthreads();
  m = fmaxf(red[0], red[1]);
  __syncthreads();
  float e = __expf(v - m);
  float s = e;
  for (int o = 32; o; o >>= 1) s += __shfl_xor(s, o, 64);
  if ((j & 63) == 0) red[wid] = s;
  __syncthreads();
  s = red[0] + red[1];
  pi[j] = e / s;
}

// chunk-parallel forward (R12, unchanged): 1 wave = 16 chunks; 80 steps; 32 mfma/step
__global__ void __launch_bounds__(64, 1) k_forward(
    const int* __restrict__ emis, const _Float16* __restrict__ expbH,
    const float* __restrict__ mB, const uint4* __restrict__ Abf_g,
    const float* __restrict__ pivec, float* __restrict__ Rbuf) {
  __shared__ __align__(16) uint4 AbfL[4 * 8 * 64];
  __shared__ float Qx[128 * 17];
  __shared__ int es[T];
  int b = blockIdx.x;
  int l = threadIdx.x;
  int c = l & 15;
  int g = l >> 4;
  for (int i = l; i < T; i += 64) es[i] = emis[b * T + i];
#pragma unroll
  for (int p = 0; p < 32; p++) AbfL[p * 64 + l] = Abf_g[p * 64 + l];
  int Jb[4];
#pragma unroll
  for (int kt = 0; kt < 4; kt++) Jb[kt] = 32 * kt + 8 * g;
  __syncthreads();
  int w0 = es[0];
  float mb0 = mB[w0];
  float a0v = pivec[2 * l] * (float)expbH[(size_t)w0 * K + 2 * l];
  float a1v = pivec[2 * l + 1] * (float)expbH[(size_t)w0 * K + 2 * l + 1];
  float am = wave_max63(fmaxf(a0v, a1v));
  float mu1 = __int_as_float(__builtin_amdgcn_readlane(__float_as_int(am), 63));
  mu1 = fmaxf(mu1, 1e-30f);
  float lmu1 = __logf(mu1);
  uint4 P0[4];
  {
    float inv = 1.0f / mu1;
#pragma unroll
    for (int kt = 0; kt < 4; kt++) {
      float v[8];
#pragma unroll
      for (int i = 0; i < 8; i++) {
        int j = Jb[kt] + i;
        v[i] = pivec[j] * (float)expbH[(size_t)w0 * K + j] * inv;
      }
      P0[kt] = make_uint4(pkh2(v[0], v[1]), pkh2(v[2], v[3]), pkh2(v[4], v[5]), pkh2(v[6], v[7]));
    }
  }
  uint4 Pk[4];
  unsigned one2 = 0x3C003C00u;
  Pk[0] = Pk[1] = Pk[2] = Pk[3] = make_uint4(one2, one2, one2, one2);
  float zprev = 1.0f, lzS = 0.f, lzE = 0.f, logS = 0.f, Cacc = 0.f;
  int cend = (c == 15) ? 78 : 79;
  for (int s = 0; s < 80; s++) {
    int t = 64 * c + s - 15;
    t = max(t, 0); t = min(t, T - 1);
    int tok = es[t];
    float mb = mB[tok];
    const uint4* ebp = (const uint4*)(expbH + (size_t)tok * K);
    uint4 eb[4];
#pragma unroll
    for (int kt = 0; kt < 4; kt++) eb[kt] = ebp[Jb[kt] >> 3];
    f32x4 acc[8];
#pragma unroll
    for (int n = 0; n < 8; n++) acc[n] = (f32x4){0.f, 0.f, 0.f, 0.f};
#pragma unroll
    for (int kt = 0; kt < 4; kt++) {
      half8 ao = __builtin_bit_cast(half8, Pk[kt]);
#pragma unroll
      for (int n = 0; n < 8; n++) {
        half8 bo = __builtin_bit_cast(half8, AbfL[(kt * 8 + n) * 64 + l]);
        acc[n] = __builtin_amdgcn_mfma_f32_16x16x32_f16(ao, bo, acc[n], 0, 0, 0);
      }
    }
#pragma unroll
    for (int n = 0; n < 8; n++) {
#pragma unroll
      for (int r = 0; r < 4; r++) Qx[17 * (16 * n + c) + 4 * g + r] = acc[n][r];
    }
    asm volatile("s_waitcnt lgkmcnt(0)" ::: "memory");
    __builtin_amdgcn_sched_barrier(0);
    float rr = __builtin_amdgcn_rcpf(fmaxf(zprev, 1e-30f));
    float lzp = __logf(fmaxf(zprev, 1e-30f));
    float pmax = 0.f, lsum = 0.f;
    uint4 newP[4];
#pragma unroll
    for (int kt = 0; kt < 4; kt++) {
      const _Float16* ebh = (const _Float16*)&eb[kt];
      float pv[8];
#pragma unroll
      for (int i = 0; i < 8; i++) {
        float q = Qx[17 * (Jb[kt] + i) + c];
        float p = q * (float)ebh[i] * rr;
        pv[i] = p;
        pmax = fmaxf(pmax, p);
        lsum += p;
      }
      newP[kt] = make_uint4(pkh2(pv[0], pv[1]), pkh2(pv[2], pv[3]),
                            pkh2(pv[4], pv[5]), pkh2(pv[6], pv[7]));
    }
    pmax = fmaxf(pmax, __shfl_xor(pmax, 16, 64));
    pmax = fmaxf(pmax, __shfl_xor(pmax, 32, 64));
    float znew = pmax;
    if (s == 15) {
      if (c == 0) {
#pragma unroll
        for (int kt = 0; kt < 4; kt++) newP[kt] = P0[kt];
        znew = 1.0f;
      }
      lzS = __logf(fmaxf(znew, 1e-30f));
    }
    bool counted = (s >= 16) && (s <= cend);
    if (counted) Cacc += lzp + mb;
    if (s == 78) {
      float ssum = lsum + __shfl_xor(lsum, 16, 64);
      ssum += __shfl_xor(ssum, 32, 64);
      logS = __logf(fmaxf(ssum, 1e-30f));
    }
    if (s == 79) lzE = __logf(fmaxf(znew, 1e-30f));
#pragma unroll
    for (int kt = 0; kt < 4; kt++) Pk[kt] = newP[kt];
    zprev = znew;
  }
  if (l < 16) {
    float Rv = Cacc - lzS;
    Rv += (c == 15) ? logS : lzE;
    if (c == 0) Rv += mb0 + lmu1;
    Rbuf[b * 16 + c] = Rv;
  }
}

__global__ void k_sll(const float* __restrict__ Rbuf, float* __restrict__ out) {
  int tid = threadIdx.x;
  __shared__ float red[4];
  float s = 0.f;
  const float* r = Rbuf + tid * 16;
#pragma unroll
  for (int q = 0; q < 16; q++) s += r[q];
#pragma unroll
  for (int o = 32; o; o >>= 1) s += __shfl_xor(s, o, 64);
  if ((tid & 63) == 0) red[tid >> 6] = s;
  __syncthreads();
  if (tid == 0) out[0] = -(red[0] + red[1] + red[2] + red[3]) / (float)B;
}

extern "C" void kernel_launch(void* const* d_in, const int* in_sizes, int n_in,
                              void* d_out, int out_size, void* d_ws, size_t ws_size,
                              hipStream_t stream) {
  const int*   emis   = (const int*)d_in[0];
  const float* initl  = (const float*)d_in[1];
  const float* tagw   = (const float*)d_in[2];
  const float* wordw  = (const float*)d_in[3];
  const float* wordb  = (const float*)d_in[4];
  const float* transw = (const float*)d_in[5];
  const float* transb = (const float*)d_in[6];
  const float* transq = (const float*)d_in[7];
  float* ws = (float*)d_ws;
  size_t off = 0;
  _Float16* scoresH = (_Float16*)(ws + off); off += (size_t)V * K / 2;
  uint4* Abf_g      = (uint4*)(ws + off);    off += 8192;   // 32 KB trans fragments
  uint4* Tbf_g      = (uint4*)(ws + off);    off += 8192;   // 32 KB tag fragments
  float* pivec      = ws + off; off += K;
  float* lse        = ws + off; off += K;
  float* pmax       = ws + off; off += (size_t)NLB * 256;
  float* psum       = ws + off; off += (size_t)NLB * 256;
  float* mB         = ws + off; off += (size_t)V + 64;
  float* Rbuf       = ws + off; off += (size_t)B * 16;
  float* out = (float*)d_out;

  hipLaunchKernelGGL(k_tagh, dim3(8), dim3(256), 0, stream, tagw, Tbf_g);
  hipLaunchKernelGGL(k_scores, dim3((V + 63) / 64), dim3(256), 0, stream, wordw, wordb, Tbf_g, scoresH);
  hipLaunchKernelGGL(k_collse, dim3(NLB), dim3(256), 0, stream, scoresH, pmax, psum);
  hipLaunchKernelGGL(k_lsefin, dim3(1), dim3(256), 0, stream, pmax, psum, lse);
  hipLaunchKernelGGL(k_expbm, dim3((V + 255) / 256), dim3(256), 0, stream, scoresH, lse, mB);
  hipLaunchKernelGGL(k_transA, dim3(K), dim3(K), 0, stream, transw, transb, transq, (unsigned short*)Abf_g);
  hipLaunchKernelGGL(k_pi, dim3(1), dim3(K), 0, stream, initl, pivec);
  hipLaunchKernelGGL(k_forward, dim3(B), dim3(64), 0, stream, emis, scoresH, mB, Abf_g, pivec, Rbuf);
  hipLaunchKernelGGL(k_sll, dim3(1), dim3(256), 0, stream, Rbuf, out);
}

// Round 15
// 152.681 us; speedup vs baseline: 6.0837x; 1.3661x over previous
//
#include <hip/hip_runtime.h>
#include <math.h>

#define K 128
#define V 50257
#define H 128
#define B 256
#define T 1024
#define NLB 256
#define WPB 197   // 256*197 >= V

typedef _Float16 half8 __attribute__((ext_vector_type(8)));
typedef float f32x4 __attribute__((ext_vector_type(4)));
typedef __fp16 fp16x2 __attribute__((ext_vector_type(2)));

__device__ __forceinline__ unsigned pkh2(float x, float y) {
  fp16x2 v = __builtin_amdgcn_cvt_pkrtz(x, y);
  return __builtin_bit_cast(unsigned, v);
}
__device__ __forceinline__ unsigned short f16b(float x) {
  fp16x2 v = __builtin_amdgcn_cvt_pkrtz(x, x);
  return (unsigned short)(__builtin_bit_cast(unsigned, v) & 0xFFFFu);
}

// DPP wave max (result valid in lane 63)
__device__ __forceinline__ float wave_max63(float x) {
  int xi;
#define MSTEP(ctrl, rm, bm)                                                          \
  xi = __builtin_amdgcn_update_dpp(__float_as_int(x), __float_as_int(x), ctrl, rm,   \
                                   bm, false);                                       \
  x = fmaxf(x, __int_as_float(xi));
  MSTEP(0x111, 0xf, 0xf)
  MSTEP(0x112, 0xf, 0xf)
  MSTEP(0x114, 0xf, 0xe)
  MSTEP(0x118, 0xf, 0xc)
  MSTEP(0x142, 0xa, 0xf)
  MSTEP(0x143, 0xc, 0xf)
#undef MSTEP
  return x;
}

// tag B-fragments (f16) for mfma_f32_16x16x32_f16 (R12-verified layout)
__global__ void __launch_bounds__(256) k_tagh(const float* __restrict__ tag_w,
                                              uint4* __restrict__ Tbf) {
  int f = blockIdx.x * 256 + threadIdx.x;
  if (f >= 2048) return;
  int lane = f & 63;
  int rest = f >> 6;
  int n = rest & 7, kt = rest >> 3;
  int k = 16 * n + (lane & 15);
  int d0 = 32 * kt + 8 * (lane >> 4);
  const float* src = tag_w + (size_t)k * K + d0;
  float4 a = *(const float4*)src;
  float4 c = *(const float4*)(src + 4);
  Tbf[f] = make_uint4(pkh2(a.x, a.y), pkh2(a.z, a.w), pkh2(c.x, c.y), pkh2(c.z, c.w));
}

// scoresH[w][k] = dot(tag[k], word[w]) + bias[w]  -- MFMA, 64 words/block
__global__ void __launch_bounds__(256) k_scores(const float* __restrict__ word_w,
                                                const float* __restrict__ word_b,
                                                const uint4* __restrict__ Tbf,
                                                _Float16* __restrict__ scoresH) {
  __shared__ __align__(16) uint4 TbfL[2048];        // 32 KB
  __shared__ __align__(16) _Float16 outT[64][136];  // 17.4 KB
  int tid = threadIdx.x;
  int wv = tid >> 6, l = tid & 63;
  int c = l & 15, g = l >> 4;
  int wbase = blockIdx.x * 64;
#pragma unroll
  for (int q = 0; q < 8; q++) TbfL[q * 256 + tid] = Tbf[q * 256 + tid];
  int wa = min(wbase + wv * 16 + c, V - 1);
  const float* wrow = word_w + (size_t)wa * K + 8 * g;
  uint4 A0, A1, A2, A3;
#define LDA(kt, dst)                                                        \
  {                                                                         \
    float4 x = *(const float4*)(wrow + 32 * kt);                            \
    float4 y = *(const float4*)(wrow + 32 * kt + 4);                        \
    dst = make_uint4(pkh2(x.x, x.y), pkh2(x.z, x.w), pkh2(y.x, y.y), pkh2(y.z, y.w)); \
  }
  LDA(0, A0) LDA(1, A1) LDA(2, A2) LDA(3, A3)
#undef LDA
  float wb[4];
#pragma unroll
  for (int r = 0; r < 4; r++) wb[r] = word_b[min(wbase + wv * 16 + 4 * g + r, V - 1)];
  __syncthreads();
  f32x4 acc[8];
#pragma unroll
  for (int n = 0; n < 8; n++) acc[n] = (f32x4){0.f, 0.f, 0.f, 0.f};
#define MK(kt, AV)                                                          \
  {                                                                         \
    half8 ao = __builtin_bit_cast(half8, AV);                               \
    _Pragma("unroll") for (int n = 0; n < 8; n++) {                         \
      half8 bo = __builtin_bit_cast(half8, TbfL[(kt * 8 + n) * 64 + l]);    \
      acc[n] = __builtin_amdgcn_mfma_f32_16x16x32_f16(ao, bo, acc[n], 0, 0, 0); \
    }                                                                       \
  }
  MK(0, A0) MK(1, A1) MK(2, A2) MK(3, A3)
#undef MK
#pragma unroll
  for (int n = 0; n < 8; n++) {
#pragma unroll
    for (int r = 0; r < 4; r++)
      outT[wv * 16 + 4 * g + r][16 * n + c] = (_Float16)(acc[n][r] + wb[r]);
  }
  __syncthreads();
#pragma unroll
  for (int q = 0; q < 4; q++) {
    int idx = q * 256 + tid;
    int wl = idx >> 4, part = idx & 15;
    int w = wbase + wl;
    if (w < V) {
      uint4 v = *(const uint4*)&outT[wl][part * 8];
      *(uint4*)&scoresH[(size_t)w * K + part * 8] = v;
    }
  }
}

// per-k online (max,sumexp) over a word slice (f16 scores in)
__global__ void __launch_bounds__(256) k_collse(const _Float16* __restrict__ scoresH,
                                                float* __restrict__ pmax,
                                                float* __restrict__ psum) {
  int tid = threadIdx.x;
  int blk = blockIdx.x;
  int k = tid & 127, half = tid >> 7;
  int w0 = blk * WPB;
  int wend = min(w0 + WPB, V);
  float m = -1e30f, s = 0.f;
  for (int w = w0 + half; w < wend; w += 2) {
    float v = (float)scoresH[(size_t)w * K + k];
    if (v > m) { s *= __expf(m - v); m = v; }
    s += __expf(v - m);
  }
  pmax[blk * 256 + tid] = m;
  psum[blk * 256 + tid] = s;
}

__global__ void k_lsefin(const float* __restrict__ pmax, const float* __restrict__ psum,
                         float* __restrict__ lse) {
  __shared__ float sm[2][K], ss[2][K];
  int tid = threadIdx.x;
  int k = tid & 127, half = tid >> 7;
  float m = -1e30f, s = 0.f;
  for (int blk = 0; blk < NLB; blk++) {
    float pm = pmax[blk * 256 + half * 128 + k];
    float pv = psum[blk * 256 + half * 128 + k];
    float nm = fmaxf(m, pm);
    s = s * __expf(m - nm) + pv * __expf(pm - nm);
    m = nm;
  }
  sm[half][k] = m;
  ss[half][k] = s;
  __syncthreads();
  if (tid < K) {
    float nm = fmaxf(sm[0][tid], sm[1][tid]);
    float st = ss[0][tid] * __expf(sm[0][tid] - nm) + ss[1][tid] * __expf(sm[1][tid] - nm);
    lse[tid] = nm + __logf(st);
  }
}

// fused: mB[w] = max_k(score-lse), then in-place scoresH -> exp(score-lse-mB)
__global__ void __launch_bounds__(256) k_expbm(_Float16* __restrict__ scoresH,
                                               const float* __restrict__ lse,
                                               float* __restrict__ mB) {
  __shared__ __align__(16) float ls[K];
  int tid = threadIdx.x;
  if (tid < K) ls[tid] = lse[tid];
  __syncthreads();
  int w = blockIdx.x * 256 + tid;
  if (w >= V) return;
  uint4* rowv = (uint4*)(scoresH + (size_t)w * K);
  float mx = -1e30f;
#pragma unroll
  for (int c = 0; c < 16; c++) {
    uint4 u = rowv[c];
    const _Float16* hp = (const _Float16*)&u;
#pragma unroll
    for (int d = 0; d < 8; d++) mx = fmaxf(mx, (float)hp[d] - ls[8 * c + d]);
  }
  mB[w] = mx;
#pragma unroll
  for (int c = 0; c < 16; c++) {
    uint4 u = rowv[c];
    const _Float16* hp = (const _Float16*)&u;
    float e[8];
#pragma unroll
    for (int d = 0; d < 8; d++) e[d] = __expf((float)hp[d] - ls[8 * c + d] - mx);
    uint4 o;
    o.x = pkh2(e[0], e[1]); o.y = pkh2(e[2], e[3]);
    o.z = pkh2(e[4], e[5]); o.w = pkh2(e[6], e[7]);
    rowv[c] = o;
  }
}

// Ahat (row-softmax of trans logits) as f16 B-fragments (R12-verified layout)
__global__ void k_transA(const float* __restrict__ trans_w, const float* __restrict__ trans_b,
                         const float* __restrict__ trans_q, unsigned short* __restrict__ AbfH) {
  __shared__ __align__(16) float qs[H];
  __shared__ float red[2];
  int i = blockIdx.x;
  int j = threadIdx.x;
  qs[j] = trans_q[j];
  __syncthreads();
  const float* wrow = trans_w + (size_t)(i * K + j) * H;
  float acc = 0.f;
#pragma unroll
  for (int h = 0; h < H; h += 4) {
    float4 w4 = *(const float4*)(wrow + h);
    float4 q4 = *(const float4*)(qs + h);
    acc += w4.x * q4.x + w4.y * q4.y + w4.z * q4.z + w4.w * q4.w;
  }
  float logit = acc + trans_b[i * K + j];
  int wid = j >> 6;
  float m = logit;
  for (int o = 32; o; o >>= 1) m = fmaxf(m, __shfl_xor(m, o, 64));
  if ((j & 63) == 0) red[wid] = m;
  __syncthreads();
  m = fmaxf(red[0], red[1]);
  __syncthreads();
  float e = __expf(logit - m);
  float s = e;
  for (int o = 32; o; o >>= 1) s += __shfl_xor(s, o, 64);
  if ((j & 63) == 0) red[wid] = s;
  __syncthreads();
  s = red[0] + red[1];
  float a = e / s;
  int kt = i >> 5;
  int g = (i & 31) >> 3;
  int lane = 16 * g + (j & 15);
  int n = j >> 4;
  int ee = i & 7;
  AbfH[(size_t)(((kt * 8 + n) * 64 + lane) * 8 + ee)] = f16b(a);
}

__global__ void k_pi(const float* __restrict__ x, float* __restrict__ pi) {
  int j = threadIdx.x;
  __shared__ float red[2];
  float v = x[j];
  int wid = j >> 6;
  float m = v;
  for (int o = 32; o; o >>= 1) m = fmaxf(m, __shfl_xor(m, o, 64));
  if ((j & 63) == 0) red[wid] = m;
  __syncthreads();
  m = fmaxf(red[0], red[1]);
  __syncthreads();
  float e = __expf(v - m);
  float s = e;
  for (int o = 32; o; o >>= 1) s += __shfl_xor(s, o, 64);
  if ((j & 63) == 0) red[wid] = s;
  __syncthreads();
  s = red[0] + red[1];
  pi[j] = e / s;
}

// chunk-parallel forward: 4 waves/block, 64 chunks of 16 counted steps; 32 steps total.
// Per wave: 16 chunks; no barriers in the T-loop; eb/mB prefetched one step ahead.
__global__ void __launch_bounds__(256, 1) k_forward(
    const int* __restrict__ emis, const _Float16* __restrict__ expbH,
    const float* __restrict__ mB, const uint4* __restrict__ Abf_g,
    const float* __restrict__ pivec, float* __restrict__ Rbuf) {
  __shared__ __align__(16) uint4 AbfL[2048];   // 32 KB shared by all waves
  __shared__ float Qx[4][128 * 17];            // 34.8 KB, per-wave
  __shared__ int es[T];
  int b = blockIdx.x;
  int tid = threadIdx.x;
  int wv = tid >> 6, l = tid & 63;
  int c16 = l & 15, g = l >> 4;
  int chunk = 16 * wv + c16;   // 0..63
  for (int i = tid; i < T; i += 256) es[i] = emis[b * T + i];
  for (int p = tid; p < 2048; p += 256) AbfL[p] = Abf_g[p];
  int Jb[4];
#pragma unroll
  for (int kt = 0; kt < 4; kt++) Jb[kt] = 32 * kt + 8 * g;
  __syncthreads();
  // exact alpha(t=0) (all waves compute; only chunk 0 uses)
  int w0 = es[0];
  float mb0 = mB[w0];
  float a0v = pivec[2 * l] * (float)expbH[(size_t)w0 * K + 2 * l];
  float a1v = pivec[2 * l + 1] * (float)expbH[(size_t)w0 * K + 2 * l + 1];
  float am = wave_max63(fmaxf(a0v, a1v));
  float mu1 = __int_as_float(__builtin_amdgcn_readlane(__float_as_int(am), 63));
  mu1 = fmaxf(mu1, 1e-30f);
  float lmu1 = __logf(mu1);
  uint4 P0[4];
  {
    float inv = 1.0f / mu1;
#pragma unroll
    for (int kt = 0; kt < 4; kt++) {
      float v[8];
#pragma unroll
      for (int i = 0; i < 8; i++) {
        int j = Jb[kt] + i;
        v[i] = pivec[j] * (float)expbH[(size_t)w0 * K + j] * inv;
      }
      P0[kt] = make_uint4(pkh2(v[0], v[1]), pkh2(v[2], v[3]), pkh2(v[4], v[5]), pkh2(v[6], v[7]));
    }
  }
  uint4 Pk[4];
  unsigned one2 = 0x3C003C00u;
  Pk[0] = Pk[1] = Pk[2] = Pk[3] = make_uint4(one2, one2, one2, one2);
  float zprev = 1.0f, lzS = 0.f, lzE = 0.f, logS = 0.f, Cacc = 0.f;
  int cend = (chunk == 63) ? 30 : 31;
  float* Qw = Qx[wv];
  // prefetch step 0's token data
  int t0 = max(16 * chunk - 15, 0);
  int tok0 = es[t0];
  float mbC = mB[tok0];
  uint4 ebC[4];
  {
    const uint4* ebp = (const uint4*)(expbH + (size_t)tok0 * K);
#pragma unroll
    for (int kt = 0; kt < 4; kt++) ebC[kt] = ebp[4 * kt + g];
  }
  for (int s = 0; s < 32; s++) {
    // prefetch step s+1 (1 full step of slack)
    int tn = 16 * chunk + s + 1 - 15;
    tn = max(tn, 0); tn = min(tn, T - 1);
    int tokN = es[tn];
    float mbN = mB[tokN];
    const uint4* ebpN = (const uint4*)(expbH + (size_t)tokN * K);
    uint4 ebN[4];
#pragma unroll
    for (int kt = 0; kt < 4; kt++) ebN[kt] = ebpN[4 * kt + g];
    // 32 mfma: acc[n] = sum_kt P[kt] * Abf[kt][n]
    f32x4 acc[8];
#pragma unroll
    for (int n = 0; n < 8; n++) acc[n] = (f32x4){0.f, 0.f, 0.f, 0.f};
#pragma unroll
    for (int kt = 0; kt < 4; kt++) {
      half8 ao = __builtin_bit_cast(half8, Pk[kt]);
#pragma unroll
      for (int n = 0; n < 8; n++) {
        half8 bo = __builtin_bit_cast(half8, AbfL[(kt * 8 + n) * 64 + l]);
        acc[n] = __builtin_amdgcn_mfma_f32_16x16x32_f16(ao, bo, acc[n], 0, 0, 0);
      }
    }
    // scatter D to Qw[j][m]
#pragma unroll
    for (int n = 0; n < 8; n++) {
#pragma unroll
      for (int r = 0; r < 4; r++) Qw[17 * (16 * n + c16) + 4 * g + r] = acc[n][r];
    }
    asm volatile("s_waitcnt lgkmcnt(0)" ::: "memory");
    __builtin_amdgcn_sched_barrier(0);
    // gather own chunk, apply eb * (1/zprev), pack f16, track max/sum
    float rr = __builtin_amdgcn_rcpf(fmaxf(zprev, 1e-30f));
    float lzp = __logf(fmaxf(zprev, 1e-30f));
    float pmax = 0.f, lsum = 0.f;
    uint4 newP[4];
#pragma unroll
    for (int kt = 0; kt < 4; kt++) {
      const _Float16* ebh = (const _Float16*)&ebC[kt];
      float pv[8];
#pragma unroll
      for (int i = 0; i < 8; i++) {
        float q = Qw[17 * (Jb[kt] + i) + c16];
        float p = q * (float)ebh[i] * rr;
        pv[i] = p;
        pmax = fmaxf(pmax, p);
        lsum += p;
      }
      newP[kt] = make_uint4(pkh2(pv[0], pv[1]), pkh2(pv[2], pv[3]),
                            pkh2(pv[4], pv[5]), pkh2(pv[6], pv[7]));
    }
    pmax = fmaxf(pmax, __shfl_xor(pmax, 16, 64));
    pmax = fmaxf(pmax, __shfl_xor(pmax, 32, 64));
    float znew = pmax;
    if (s == 15) {
      if (chunk == 0) {
#pragma unroll
        for (int kt = 0; kt < 4; kt++) newP[kt] = P0[kt];
        znew = 1.0f;
      }
      lzS = __logf(fmaxf(znew, 1e-30f));
    }
    bool counted = (s >= 16) && (s <= cend);
    if (counted) Cacc += lzp + mbC;
    if (s == 30) {
      float ssum = lsum + __shfl_xor(lsum, 16, 64);
      ssum += __shfl_xor(ssum, 32, 64);
      logS = __logf(fmaxf(ssum, 1e-30f));
    }
    if (s == 31) lzE = __logf(fmaxf(znew, 1e-30f));
#pragma unroll
    for (int kt = 0; kt < 4; kt++) Pk[kt] = newP[kt];
    zprev = znew;
#pragma unroll
    for (int kt = 0; kt < 4; kt++) ebC[kt] = ebN[kt];
    mbC = mbN;
  }
  if (l < 16) {
    float Rv = Cacc - lzS;
    Rv += (chunk == 63) ? logS : lzE;
    if (chunk == 0) Rv += mb0 + lmu1;
    Rbuf[b * 64 + chunk] = Rv;
  }
}

// sll per chain = sum of 64 chunk R's; loss = -mean
__global__ void k_sll(const float* __restrict__ Rbuf, float* __restrict__ out) {
  int tid = threadIdx.x;
  __shared__ float red[4];
  float s = 0.f;
  const float* r = Rbuf + (size_t)tid * 64;
#pragma unroll
  for (int q = 0; q < 64; q++) s += r[q];
#pragma unroll
  for (int o = 32; o; o >>= 1) s += __shfl_xor(s, o, 64);
  if ((tid & 63) == 0) red[tid >> 6] = s;
  __syncthreads();
  if (tid == 0) out[0] = -(red[0] + red[1] + red[2] + red[3]) / (float)B;
}

extern "C" void kernel_launch(void* const* d_in, const int* in_sizes, int n_in,
                              void* d_out, int out_size, void* d_ws, size_t ws_size,
                              hipStream_t stream) {
  const int*   emis   = (const int*)d_in[0];
  const float* initl  = (const float*)d_in[1];
  const float* tagw   = (const float*)d_in[2];
  const float* wordw  = (const float*)d_in[3];
  const float* wordb  = (const float*)d_in[4];
  const float* transw = (const float*)d_in[5];
  const float* transb = (const float*)d_in[6];
  const float* transq = (const float*)d_in[7];
  float* ws = (float*)d_ws;
  size_t off = 0;
  _Float16* scoresH = (_Float16*)(ws + off); off += (size_t)V * K / 2;
  uint4* Abf_g      = (uint4*)(ws + off);    off += 8192;
  uint4* Tbf_g      = (uint4*)(ws + off);    off += 8192;
  float* pivec      = ws + off; off += K;
  float* lse        = ws + off; off += K;
  float* pmax       = ws + off; off += (size_t)NLB * 256;
  float* psum       = ws + off; off += (size_t)NLB * 256;
  float* mB         = ws + off; off += (size_t)V + 64;
  float* Rbuf       = ws + off; off += (size_t)B * 64;
  float* out = (float*)d_out;

  hipLaunchKernelGGL(k_tagh, dim3(8), dim3(256), 0, stream, tagw, Tbf_g);
  hipLaunchKernelGGL(k_scores, dim3((V + 63) / 64), dim3(256), 0, stream, wordw, wordb, Tbf_g, scoresH);
  hipLaunchKernelGGL(k_collse, dim3(NLB), dim3(256), 0, stream, scoresH, pmax, psum);
  hipLaunchKernelGGL(k_lsefin, dim3(1), dim3(256), 0, stream, pmax, psum, lse);
  hipLaunchKernelGGL(k_expbm, dim3((V + 255) / 256), dim3(256), 0, stream, scoresH, lse, mB);
  hipLaunchKernelGGL(k_transA, dim3(K), dim3(K), 0, stream, transw, transb, transq, (unsigned short*)Abf_g);
  hipLaunchKernelGGL(k_pi, dim3(1), dim3(K), 0, stream, initl, pivec);
  hipLaunchKernelGGL(k_forward, dim3(B), dim3(256), 0, stream, emis, scoresH, mB, Abf_g, pivec, Rbuf);
  hipLaunchKernelGGL(k_sll, dim3(1), dim3(256), 0, stream, Rbuf, out);
}